// Round 1
// baseline (157.982 us; speedup 1.0000x reference)
//
#include <hip/hip_runtime.h>
#include <hip/hip_bf16.h>

// TwinPolicy: node MLP -> edge MLP (restructured: concat-GEMM split into
// A = h@We1a.T + be1, B = h@We1b.T; per-edge s = dot(relu(A[src]+B[dst]), We2)+be2)
// -> global softmax over 4096x4096 grid with E=131072 finite entries.

#define N_NODES 4096
#define E_EDGES 131072
#define IN_DIM  1024
#define DHID    256

// ---------------------------------------------------------------------------
// f32 SGEMM (NT): C[M x Nout] = act(Arow[M x K] @ Wrow[Nout x K]^T + bias)
// 64x64 tile, BK=16, 256 threads, 4x4 per-thread, double-buffered LDS.
// grid = (M/64, Nout/64)
// ---------------------------------------------------------------------------
__global__ __launch_bounds__(256)
void gemm_nt_kernel(const float* __restrict__ A, int lda,
                    const float* __restrict__ W, int ldw,
                    const float* __restrict__ bias,
                    float* __restrict__ C, int ldc,
                    int K, int relu)
{
    __shared__ float As[2][16][64];
    __shared__ float Ws[2][16][64];
    const int tid = threadIdx.x;
    const int tx = tid & 15;         // output col group
    const int ty = tid >> 4;         // output row group
    const size_t brow = (size_t)blockIdx.x * 64;
    const size_t bcol = (size_t)blockIdx.y * 64;

    // staging: thread -> (row = tid>>2, k4 = (tid&3)*4), one float4 each
    const int lrow = tid >> 2;
    const int lk   = (tid & 3) << 2;
    const float* Ap = A + (brow + (size_t)lrow) * (size_t)lda + lk;
    const float* Wp = W + (bcol + (size_t)lrow) * (size_t)ldw + lk;

    float4 ra = *(const float4*)Ap;
    float4 rw = *(const float4*)Wp;
    As[0][lk+0][lrow] = ra.x; As[0][lk+1][lrow] = ra.y;
    As[0][lk+2][lrow] = ra.z; As[0][lk+3][lrow] = ra.w;
    Ws[0][lk+0][lrow] = rw.x; Ws[0][lk+1][lrow] = rw.y;
    Ws[0][lk+2][lrow] = rw.z; Ws[0][lk+3][lrow] = rw.w;
    __syncthreads();

    float acc[4][4] = {};
    const int nk = K >> 4;
    for (int kc = 0; kc < nk; ++kc) {
        const int cur = kc & 1;
        if (kc + 1 < nk) {
            ra = *(const float4*)(Ap + (size_t)(kc + 1) * 16);
            rw = *(const float4*)(Wp + (size_t)(kc + 1) * 16);
        }
        #pragma unroll
        for (int k = 0; k < 16; ++k) {
            const float4 a4 = *(const float4*)&As[cur][k][ty << 2];
            const float4 w4 = *(const float4*)&Ws[cur][k][tx << 2];
            const float av[4] = {a4.x, a4.y, a4.z, a4.w};
            const float wv[4] = {w4.x, w4.y, w4.z, w4.w};
            #pragma unroll
            for (int i = 0; i < 4; ++i)
                #pragma unroll
                for (int j = 0; j < 4; ++j)
                    acc[i][j] += av[i] * wv[j];
        }
        if (kc + 1 < nk) {
            const int nxt = cur ^ 1;
            As[nxt][lk+0][lrow] = ra.x; As[nxt][lk+1][lrow] = ra.y;
            As[nxt][lk+2][lrow] = ra.z; As[nxt][lk+3][lrow] = ra.w;
            Ws[nxt][lk+0][lrow] = rw.x; Ws[nxt][lk+1][lrow] = rw.y;
            Ws[nxt][lk+2][lrow] = rw.z; Ws[nxt][lk+3][lrow] = rw.w;
            __syncthreads();
        }
    }

    // epilogue: + bias (may be null), optional relu, float4 stores
    float bv[4];
    #pragma unroll
    for (int j = 0; j < 4; ++j)
        bv[j] = bias ? bias[bcol + (tx << 2) + j] : 0.0f;
    #pragma unroll
    for (int i = 0; i < 4; ++i) {
        float4 v;
        v.x = acc[i][0] + bv[0];
        v.y = acc[i][1] + bv[1];
        v.z = acc[i][2] + bv[2];
        v.w = acc[i][3] + bv[3];
        if (relu) {
            v.x = fmaxf(v.x, 0.0f); v.y = fmaxf(v.y, 0.0f);
            v.z = fmaxf(v.z, 0.0f); v.w = fmaxf(v.w, 0.0f);
        }
        float* cp = C + (brow + (size_t)(ty << 2) + i) * (size_t)ldc + bcol + (tx << 2);
        *(float4*)cp = v;
    }
}

// ---------------------------------------------------------------------------
// Edge MLP: one wave per edge. Lane l holds channels [4l, 4l+3] as float4.
// s[e] = dot(relu(A[src]+B[dst]), We2) + be2
// ---------------------------------------------------------------------------
__global__ __launch_bounds__(256)
void edge_mlp_kernel(const float* __restrict__ Abuf,
                     const float* __restrict__ Bbuf,
                     const int* __restrict__ idx,
                     const float* __restrict__ We2,
                     const float* __restrict__ be2p,
                     float* __restrict__ s, int n)
{
    const int gtid = blockIdx.x * blockDim.x + threadIdx.x;
    const int wave = gtid >> 6;
    const int lane = threadIdx.x & 63;
    const int nwaves = (gridDim.x * blockDim.x) >> 6;
    const float4 w2 = ((const float4*)We2)[lane];
    const float be2 = be2p[0];

    for (int e = wave; e < n; e += nwaves) {
        const int src = idx[2 * e];
        const int dst = idx[2 * e + 1];
        const float4 a = ((const float4*)Abuf)[(size_t)src * 64 + lane];
        const float4 b = ((const float4*)Bbuf)[(size_t)dst * 64 + lane];
        float p = fmaxf(a.x + b.x, 0.0f) * w2.x
                + fmaxf(a.y + b.y, 0.0f) * w2.y
                + fmaxf(a.z + b.z, 0.0f) * w2.z
                + fmaxf(a.w + b.w, 0.0f) * w2.w;
        #pragma unroll
        for (int m = 32; m > 0; m >>= 1)
            p += __shfl_xor(p, m, 64);
        if (lane == 0) s[e] = p + be2;
    }
}

// ---------------------------------------------------------------------------
// Reductions (deterministic trees)
// ---------------------------------------------------------------------------
__global__ __launch_bounds__(256)
void reduce_max_part(const float* __restrict__ s, int n, float* __restrict__ part)
{
    __shared__ float sm[256];
    float m = -3.0e38f;
    for (int i = blockIdx.x * blockDim.x + threadIdx.x; i < n; i += blockDim.x * gridDim.x)
        m = fmaxf(m, s[i]);
    sm[threadIdx.x] = m;
    __syncthreads();
    for (int st = 128; st > 0; st >>= 1) {
        if (threadIdx.x < st) sm[threadIdx.x] = fmaxf(sm[threadIdx.x], sm[threadIdx.x + st]);
        __syncthreads();
    }
    if (threadIdx.x == 0) part[blockIdx.x] = sm[0];
}

__global__ __launch_bounds__(256)
void reduce_max_fin(const float* __restrict__ part, float* __restrict__ g)
{
    __shared__ float sm[256];
    sm[threadIdx.x] = part[threadIdx.x];
    __syncthreads();
    for (int st = 128; st > 0; st >>= 1) {
        if (threadIdx.x < st) sm[threadIdx.x] = fmaxf(sm[threadIdx.x], sm[threadIdx.x + st]);
        __syncthreads();
    }
    if (threadIdx.x == 0) g[0] = sm[0];
}

__global__ __launch_bounds__(256)
void reduce_sumexp_part(const float* __restrict__ s, const float* __restrict__ g,
                        int n, float* __restrict__ part)
{
    __shared__ float sm[256];
    const float gm = g[0];
    float a = 0.0f;
    for (int i = blockIdx.x * blockDim.x + threadIdx.x; i < n; i += blockDim.x * gridDim.x)
        a += expf(s[i] - gm);
    sm[threadIdx.x] = a;
    __syncthreads();
    for (int st = 128; st > 0; st >>= 1) {
        if (threadIdx.x < st) sm[threadIdx.x] += sm[threadIdx.x + st];
        __syncthreads();
    }
    if (threadIdx.x == 0) part[blockIdx.x] = sm[0];
}

__global__ __launch_bounds__(256)
void reduce_sum_fin(const float* __restrict__ part, float* __restrict__ g1)
{
    __shared__ float sm[256];
    sm[threadIdx.x] = part[threadIdx.x];
    __syncthreads();
    for (int st = 128; st > 0; st >>= 1) {
        if (threadIdx.x < st) sm[threadIdx.x] += sm[threadIdx.x + st];
        __syncthreads();
    }
    if (threadIdx.x == 0) g1[0] = sm[0];
}

// ---------------------------------------------------------------------------
// Scatter probs: out[src*N + dst] = exp(s - max) / sum  (edges are unique)
// ---------------------------------------------------------------------------
__global__ __launch_bounds__(256)
void scatter_probs(const float* __restrict__ s, const int* __restrict__ idx,
                   const float* __restrict__ g, float* __restrict__ out, int n)
{
    const int e = blockIdx.x * blockDim.x + threadIdx.x;
    if (e < n) {
        const float p = expf(s[e] - g[0]) / g[1];
        out[(size_t)idx[2 * e] * N_NODES + idx[2 * e + 1]] = p;
    }
}

extern "C" void kernel_launch(void* const* d_in, const int* in_sizes, int n_in,
                              void* d_out, int out_size, void* d_ws, size_t ws_size,
                              hipStream_t stream)
{
    const float* ideal = (const float*)d_in[0];   // 4096 x 1024
    const int*   idx   = (const int*)d_in[1];     // E x 2 (int32)
    const float* W1    = (const float*)d_in[2];   // 256 x 1024
    const float* b1    = (const float*)d_in[3];   // 256
    const float* W2    = (const float*)d_in[4];   // 256 x 256
    const float* b2    = (const float*)d_in[5];   // 256
    const float* We1   = (const float*)d_in[6];   // 256 x 512
    const float* be1   = (const float*)d_in[7];   // 256
    const float* We2   = (const float*)d_in[8];   // 1 x 256
    const float* be2   = (const float*)d_in[9];   // 1
    float* out = (float*)d_out;

    // workspace layout (floats): h1 | h | A | B | s | part(512) | g(2)
    float* ws   = (float*)d_ws;
    float* h1   = ws;
    float* h    = ws + 1 * 1048576;
    float* Abuf = ws + 2 * 1048576;
    float* Bbuf = ws + 3 * 1048576;
    float* sbuf = ws + 4 * 1048576;
    float* part = sbuf + E_EDGES;
    float* g    = part + 512;

    dim3 blk(256);
    // h1 = relu(x @ W1.T + b1)            (4096x1024)@(1024x256)
    gemm_nt_kernel<<<dim3(N_NODES / 64, DHID / 64), blk, 0, stream>>>(
        ideal, IN_DIM, W1, IN_DIM, b1, h1, DHID, IN_DIM, 1);
    // h = h1 @ W2.T + b2                  (4096x256)@(256x256)
    gemm_nt_kernel<<<dim3(N_NODES / 64, DHID / 64), blk, 0, stream>>>(
        h1, DHID, W2, DHID, b2, h, DHID, DHID, 0);
    // A = h @ We1[:, :256].T + be1
    gemm_nt_kernel<<<dim3(N_NODES / 64, DHID / 64), blk, 0, stream>>>(
        h, DHID, We1, 2 * DHID, be1, Abuf, DHID, DHID, 0);
    // B = h @ We1[:, 256:].T
    gemm_nt_kernel<<<dim3(N_NODES / 64, DHID / 64), blk, 0, stream>>>(
        h, DHID, We1 + DHID, 2 * DHID, nullptr, Bbuf, DHID, DHID, 0);

    // per-edge scores
    edge_mlp_kernel<<<dim3(1024), blk, 0, stream>>>(Abuf, Bbuf, idx, We2, be2, sbuf, E_EDGES);

    // softmax stats
    reduce_max_part<<<dim3(256), blk, 0, stream>>>(sbuf, E_EDGES, part);
    reduce_max_fin<<<dim3(1), blk, 0, stream>>>(part, g);
    reduce_sumexp_part<<<dim3(256), blk, 0, stream>>>(sbuf, g, E_EDGES, part + 256);
    reduce_sum_fin<<<dim3(1), blk, 0, stream>>>(part + 256, g + 1);

    // output: zeros everywhere, probs at edge slots
    hipMemsetAsync(d_out, 0, (size_t)out_size * sizeof(float), stream);
    scatter_probs<<<dim3(E_EDGES / 256), blk, 0, stream>>>(sbuf, idx, g, out, E_EDGES);
}

// Round 2
// 141.430 us; speedup vs baseline: 1.1170x; 1.1170x over previous
//
#include <hip/hip_runtime.h>
#include <hip/hip_bf16.h>

// TwinPolicy restructured:
//   h1 = relu(x @ W1.T + b1)                       (split-bf16 MFMA GEMM, K=1024)
//   AB = h1 @ [We1a@W2 ; We1b@W2].T + [be1+We1a@b2 ; We1b@b2]   (MFMA GEMM, N=512)
//   s[e] = dot(relu(AB[src,:256] + AB[dst,256:]), We2) + be2
//   out = softmax over 4096x4096 grid (finite only at E edge slots)
//
// Split-bf16: each f32 operand X = Xh + Xl (bf16 pair); X@W ~= Xh@Wh + Xh@Wl + Xl@Wh
// (drop Xl@Wl, ~2^-18 relative). Implemented as one bf16 GEMM with 3 K-segments.

typedef unsigned short u16;
typedef unsigned int   u32;
typedef __attribute__((ext_vector_type(8))) short bf16x8;
typedef __attribute__((ext_vector_type(4))) float f32x4;

#define N_NODES 4096
#define E_EDGES 131072
#define AS1 __attribute__((address_space(1)))
#define AS3 __attribute__((address_space(3)))

__device__ __forceinline__ u16 f2bf(float f) {
    u32 u = __float_as_uint(f);
    return (u16)((u + 0x7FFFu + ((u >> 16) & 1u)) >> 16);
}
__device__ __forceinline__ float bf2f(u16 h) {
    return __uint_as_float(((u32)h) << 16);
}

// ---------------------------------------------------------------------------
// Split f32 [M][K] into hi/lo bf16, packed MFMA-ready:
// elem(row,k) -> [p=row>>6][kc=k>>6][kb=(k>>3)&7][r=row&63][e=k&7]
// gid = ((p*KC+kc)*8+kb)*64 + r, each thread handles e=0..7 (16B write).
// grid = M*K/8/256, kcs = log2(K/64)
// ---------------------------------------------------------------------------
__global__ __launch_bounds__(256)
void split_pack(const float* __restrict__ in, u16* __restrict__ hi,
                u16* __restrict__ lo, int K, int kcs)
{
    const int gid = blockIdx.x * 256 + threadIdx.x;
    const int r   = gid & 63;
    const int kb  = (gid >> 6) & 7;
    const int pkc = gid >> 9;
    const int kc  = pkc & ((1 << kcs) - 1);
    const int p   = pkc >> kcs;
    const size_t row = ((size_t)p << 6) | r;
    const int k0 = (kc << 6) | (kb << 3);

    const float* src = in + row * (size_t)K + k0;
    const float4 v0 = *(const float4*)src;
    const float4 v1 = *(const float4*)(src + 4);
    const float vv[8] = {v0.x, v0.y, v0.z, v0.w, v1.x, v1.y, v1.z, v1.w};

    u32 hw[4], lw[4];
    #pragma unroll
    for (int q = 0; q < 4; ++q) {
        u16 h0 = f2bf(vv[2 * q]);
        u16 h1 = f2bf(vv[2 * q + 1]);
        u16 l0 = f2bf(vv[2 * q] - bf2f(h0));
        u16 l1 = f2bf(vv[2 * q + 1] - bf2f(h1));
        hw[q] = (u32)h0 | ((u32)h1 << 16);
        lw[q] = (u32)l0 | ((u32)l1 << 16);
    }
    uint4 hv = {hw[0], hw[1], hw[2], hw[3]};
    uint4 lv = {lw[0], lw[1], lw[2], lw[3]};
    *(uint4*)(hi + (size_t)gid * 8) = hv;
    *(uint4*)(lo + (size_t)gid * 8) = lv;
}

// ---------------------------------------------------------------------------
// Wab[r][c] (512x256): r<256 -> We1a@W2 row r, r>=256 -> We1b@W2 row r-256
// grid 64 blocks x 256 thr; block handles 8 consecutive r.
// ---------------------------------------------------------------------------
__global__ __launch_bounds__(256)
void fold_wab(const float* __restrict__ We1, const float* __restrict__ W2,
              float* __restrict__ Wab)
{
    const int r0 = blockIdx.x * 8;
    const int c  = threadIdx.x;
    float acc[8] = {};
    for (int k = 0; k < 256; ++k) {
        const float w2 = W2[k * 256 + c];
        #pragma unroll
        for (int j = 0; j < 8; ++j) {
            const int r = r0 + j;
            const int i = r & 255;
            const int koff = (r >> 8) << 8;
            acc[j] += We1[(size_t)i * 512 + koff + k] * w2;
        }
    }
    #pragma unroll
    for (int j = 0; j < 8; ++j)
        Wab[(size_t)(r0 + j) * 256 + c] = acc[j];
}

// bab[r] = (r<256 ? be1[r] : 0) + dot(We1_row_part, b2);  grid 2 x 256
__global__ __launch_bounds__(256)
void fold_bab(const float* __restrict__ We1, const float* __restrict__ b2,
              const float* __restrict__ be1, float* __restrict__ bab)
{
    const int r = blockIdx.x * 256 + threadIdx.x;
    const int i = r & 255;
    const int koff = (r >> 8) << 8;
    float acc = (r < 256) ? be1[i] : 0.0f;
    for (int k = 0; k < 256; ++k)
        acc += We1[(size_t)i * 512 + koff + k] * b2[k];
    bab[r] = acc;
}

// ---------------------------------------------------------------------------
// Split-bf16 MFMA GEMM: C[M x Nout] = act(A @ W.T + bias)
// A,W given as packed hi/lo. 64x64 tile, BK=64, 4 waves (wave = 16-col strip),
// 16x16x32 bf16 MFMA, double-buffered LDS staged via global_load_lds(16B).
// Logical K-chunks: [0,KC)=(Ah,Wh), [KC,2KC)=(Ah,Wl), [2KC,3KC)=(Al,Wh).
// grid = (M/64, Nout/64); KC = K/64 (power of 2).
// ---------------------------------------------------------------------------
__global__ __launch_bounds__(256)
void mfma_gemm(const u16* __restrict__ Ah, const u16* __restrict__ Al,
               const u16* __restrict__ Wh, const u16* __restrict__ Wl,
               const float* __restrict__ bias, float* __restrict__ C,
               int Nout, int KC, int relu)
{
    __shared__ u16 As[2][4096];
    __shared__ u16 Bs[2][4096];
    const int tid  = threadIdx.x;
    const int wv   = tid >> 6;
    const int lane = tid & 63;
    const int bp   = blockIdx.x;
    const int bn   = blockIdx.y;
    const int NT   = 3 * KC;

    auto stage = [&](int b, int t) {
        const u16* pa = (t < 2 * KC) ? Ah : Al;
        const u16* pw = (t >= KC && t < 2 * KC) ? Wl : Wh;
        const int kc = t & (KC - 1);
        const u16* ga = pa + (((size_t)bp * KC + kc) << 12);
        const u16* gw = pw + (((size_t)bn * KC + kc) << 12);
        #pragma unroll
        for (int c = 0; c < 2; ++c) {
            const int ch = (wv << 1) + c;
            __builtin_amdgcn_global_load_lds(
                (const AS1 u32*)(ga + (ch << 9) + (lane << 3)),
                (AS3 u32*)(&As[b][ch << 9]), 16, 0, 0);
            __builtin_amdgcn_global_load_lds(
                (const AS1 u32*)(gw + (ch << 9) + (lane << 3)),
                (AS3 u32*)(&Bs[b][ch << 9]), 16, 0, 0);
        }
    };

    f32x4 acc[4];
    #pragma unroll
    for (int m = 0; m < 4; ++m) acc[m] = (f32x4){0.f, 0.f, 0.f, 0.f};

    const int kq  = lane >> 4;   // k-quarter
    const int r16 = lane & 15;   // row/col within fragment

    auto compute = [&](int b) {
        #pragma unroll
        for (int s = 0; s < 2; ++s) {
            const int kb = (s << 2) + kq;
            const bf16x8 bf = *(const bf16x8*)&Bs[b][((kb << 6) + (wv << 4) + r16) << 3];
            #pragma unroll
            for (int m = 0; m < 4; ++m) {
                const bf16x8 af = *(const bf16x8*)&As[b][((kb << 6) + (m << 4) + r16) << 3];
                acc[m] = __builtin_amdgcn_mfma_f32_16x16x32_bf16(af, bf, acc[m], 0, 0, 0);
            }
        }
    };

    stage(0, 0);
    __syncthreads();
    int buf = 0;
    for (int t = 0; t < NT; ++t) {
        if (t + 1 < NT) stage(buf ^ 1, t + 1);
        compute(buf);
        __syncthreads();
        buf ^= 1;
    }

    // C/D layout: col = lane&15, row = (lane>>4)*4 + j  [m89-verified]
    const int col  = (bn << 6) + (wv << 4) + r16;
    const float bv = bias[col];
    const int row0 = (bp << 6) + (kq << 2);
    #pragma unroll
    for (int m = 0; m < 4; ++m) {
        #pragma unroll
        for (int j = 0; j < 4; ++j) {
            float v = acc[m][j] + bv;
            if (relu) v = fmaxf(v, 0.0f);
            C[(size_t)(row0 + (m << 4) + j) * Nout + col] = v;
        }
    }
}

// ---------------------------------------------------------------------------
// Edge MLP: one wave per edge; lane l holds channels [4l,4l+3].
// s[e] = dot(relu(AB[src,0:256] + AB[dst,256:512]), We2) + be2
// ---------------------------------------------------------------------------
__global__ __launch_bounds__(256)
void edge_mlp(const float* __restrict__ AB, const int* __restrict__ idx,
              const float* __restrict__ We2, const float* __restrict__ be2p,
              float* __restrict__ s, int n)
{
    const int gtid = blockIdx.x * blockDim.x + threadIdx.x;
    const int wave = gtid >> 6;
    const int lane = threadIdx.x & 63;
    const int nwaves = (gridDim.x * blockDim.x) >> 6;
    const float4 w2 = ((const float4*)We2)[lane];
    const float be2 = be2p[0];

    for (int e = wave; e < n; e += nwaves) {
        const int src = idx[2 * e];
        const int dst = idx[2 * e + 1];
        const float4 a = *(const float4*)(AB + ((size_t)src << 9) + (lane << 2));
        const float4 b = *(const float4*)(AB + ((size_t)dst << 9) + 256 + (lane << 2));
        float p = fmaxf(a.x + b.x, 0.0f) * w2.x
                + fmaxf(a.y + b.y, 0.0f) * w2.y
                + fmaxf(a.z + b.z, 0.0f) * w2.z
                + fmaxf(a.w + b.w, 0.0f) * w2.w;
        #pragma unroll
        for (int m = 32; m > 0; m >>= 1)
            p += __shfl_xor(p, m, 64);
        if (lane == 0) s[e] = p + be2;
    }
}

// ---------------------------------------------------------------------------
// Softmax pieces (deterministic trees)
// ---------------------------------------------------------------------------
__global__ __launch_bounds__(256)
void reduce_max_part(const float* __restrict__ s, int n, float* __restrict__ part)
{
    __shared__ float sm[256];
    float m = -3.0e38f;
    for (int i = blockIdx.x * 256 + threadIdx.x; i < n; i += 256 * gridDim.x)
        m = fmaxf(m, s[i]);
    sm[threadIdx.x] = m;
    __syncthreads();
    for (int st = 128; st > 0; st >>= 1) {
        if (threadIdx.x < st) sm[threadIdx.x] = fmaxf(sm[threadIdx.x], sm[threadIdx.x + st]);
        __syncthreads();
    }
    if (threadIdx.x == 0) part[blockIdx.x] = sm[0];
}

// fused: finalize max (each block redundantly) + partial sum of exp
__global__ __launch_bounds__(256)
void sumexp_part(const float* __restrict__ s, const float* __restrict__ part,
                 int n, float* __restrict__ part2, float* __restrict__ g)
{
    __shared__ float sm[256];
    sm[threadIdx.x] = part[threadIdx.x];
    __syncthreads();
    for (int st = 128; st > 0; st >>= 1) {
        if (threadIdx.x < st) sm[threadIdx.x] = fmaxf(sm[threadIdx.x], sm[threadIdx.x + st]);
        __syncthreads();
    }
    const float gm = sm[0];
    __syncthreads();
    float a = 0.0f;
    for (int i = blockIdx.x * 256 + threadIdx.x; i < n; i += 256 * gridDim.x)
        a += expf(s[i] - gm);
    sm[threadIdx.x] = a;
    __syncthreads();
    for (int st = 128; st > 0; st >>= 1) {
        if (threadIdx.x < st) sm[threadIdx.x] += sm[threadIdx.x + st];
        __syncthreads();
    }
    if (threadIdx.x == 0) {
        part2[blockIdx.x] = sm[0];
        if (blockIdx.x == 0) g[0] = gm;
    }
}

// fused: finalize sum (each block redundantly) + scatter probs
__global__ __launch_bounds__(256)
void scatter_probs(const float* __restrict__ s, const int* __restrict__ idx,
                   const float* __restrict__ part2, const float* __restrict__ g,
                   float* __restrict__ out, int n)
{
    __shared__ float sm[256];
    sm[threadIdx.x] = part2[threadIdx.x];
    __syncthreads();
    for (int st = 128; st > 0; st >>= 1) {
        if (threadIdx.x < st) sm[threadIdx.x] += sm[threadIdx.x + st];
        __syncthreads();
    }
    const float Z = sm[0];
    const float gm = g[0];
    const int e = blockIdx.x * 256 + threadIdx.x;
    if (e < n) {
        out[(size_t)idx[2 * e] * N_NODES + idx[2 * e + 1]] = expf(s[e] - gm) / Z;
    }
}

// ---------------------------------------------------------------------------
extern "C" void kernel_launch(void* const* d_in, const int* in_sizes, int n_in,
                              void* d_out, int out_size, void* d_ws, size_t ws_size,
                              hipStream_t stream)
{
    const float* ideal = (const float*)d_in[0];   // 4096 x 1024
    const int*   idx   = (const int*)d_in[1];     // E x 2
    const float* W1    = (const float*)d_in[2];   // 256 x 1024
    const float* b1    = (const float*)d_in[3];   // 256
    const float* W2    = (const float*)d_in[4];   // 256 x 256
    const float* b2    = (const float*)d_in[5];   // 256
    const float* We1   = (const float*)d_in[6];   // 256 x 512
    const float* be1   = (const float*)d_in[7];   // 256
    const float* We2   = (const float*)d_in[8];   // 256
    const float* be2   = (const float*)d_in[9];   // 1
    float* out = (float*)d_out;

    // workspace layout (byte offsets); aliases exploit liveness:
    //   [0,8M):   xh_pack   -> later AB (4096x512 f32)
    //   [8M,16M): xl_pack   -> later h1h(2M) h1l(2M) wabh(256K) wabl(256K)
    //   [16M,20M): h1 (4096x256 f32)
    //   [20M,21M): w1h(512K) w1l(512K)
    //   [21M,22M): Wab(512K) bab(2K)
    //   [22M,...): sbuf(512K) part(256f) part2(256f) g(1f)
    char* W = (char*)d_ws;
    u16*   xh   = (u16*)(W);
    u16*   xl   = (u16*)(W + (8u << 20));
    float* AB   = (float*)(W);                       // alias over xh
    u16*   h1h  = (u16*)(W + (8u << 20));            // alias over xl
    u16*   h1l  = (u16*)(W + (10u << 20));
    u16*   wabh = (u16*)(W + (12u << 20));
    u16*   wabl = (u16*)(W + (12u << 20) + (256u << 10));
    float* h1   = (float*)(W + (16u << 20));
    u16*   w1h  = (u16*)(W + (20u << 20));
    u16*   w1l  = (u16*)(W + (20u << 20) + (512u << 10));
    float* Wab  = (float*)(W + (21u << 20));
    float* bab  = (float*)(W + (21u << 20) + (512u << 10));
    float* sbuf = (float*)(W + (22u << 20));
    float* part = sbuf + E_EDGES;
    float* part2 = part + 256;
    float* g    = part + 512;

    // node MLP (layer 1) in split-bf16
    split_pack<<<2048, 256, 0, stream>>>(ideal, xh, xl, 1024, 4);
    split_pack<<<128, 256, 0, stream>>>(W1, w1h, w1l, 1024, 4);
    fold_wab<<<64, 256, 0, stream>>>(We1, W2, Wab);
    fold_bab<<<2, 256, 0, stream>>>(We1, b2, be1, bab);
    mfma_gemm<<<dim3(64, 4), 256, 0, stream>>>(xh, xl, w1h, w1l, b1, h1, 256, 16, 1);

    // folded layer-2 + edge-linear in split-bf16 (N = 512: [A | B])
    split_pack<<<512, 256, 0, stream>>>(h1, h1h, h1l, 256, 2);
    split_pack<<<64, 256, 0, stream>>>(Wab, wabh, wabl, 256, 2);
    mfma_gemm<<<dim3(64, 8), 256, 0, stream>>>(h1h, h1l, wabh, wabl, bab, AB, 512, 4, 0);

    // per-edge scores + global softmax + scatter
    edge_mlp<<<1024, 256, 0, stream>>>(AB, idx, We2, be2, sbuf, E_EDGES);
    reduce_max_part<<<256, 256, 0, stream>>>(sbuf, E_EDGES, part);
    sumexp_part<<<256, 256, 0, stream>>>(sbuf, part, E_EDGES, part2, g);
    hipMemsetAsync(d_out, 0, (size_t)out_size * sizeof(float), stream);
    scatter_probs<<<512, 256, 0, stream>>>(sbuf, idx, part2, g, out, E_EDGES);
}

// Round 3
// 109.048 us; speedup vs baseline: 1.4487x; 1.2970x over previous
//
#include <hip/hip_runtime.h>
#include <hip/hip_bf16.h>

// TwinPolicy, pure-bf16 MFMA pipeline:
//   h1p = pack(relu(x @ W1.T + b1))               (bf16 MFMA GEMM, K=1024, packed epilogue)
//   ABbf = bf16(h1 @ [We1a@W2 ; We1b@W2].T + bab) (bf16 MFMA GEMM, N=512, bf16 row-major out)
//   s[e] = dot(relu(AB[src,:256] + AB[dst,256:]), We2) + be2   (+ fused block max)
//   out = softmax over 4096x4096 grid (finite only at E edge slots)
// Precision: probs ~ 7.6e-6 so Δp ≈ p·Δs; bf16 GEMM error Δs ~ 3e-3 -> Δp ~ 2e-8 (< 1 ulp out).

typedef unsigned short u16;
typedef unsigned int   u32;
typedef __attribute__((ext_vector_type(8))) short bf16x8;
typedef __attribute__((ext_vector_type(4))) float f32x4;

#define N_NODES 4096
#define E_EDGES 131072
#define AS1 __attribute__((address_space(1)))
#define AS3 __attribute__((address_space(3)))

__device__ __forceinline__ u16 f2bf(float f) {
    u32 u = __float_as_uint(f);
    return (u16)((u + 0x7FFFu + ((u >> 16) & 1u)) >> 16);
}
__device__ __forceinline__ float bf2f(u16 h) {
    return __uint_as_float(((u32)h) << 16);
}

// ---------------------------------------------------------------------------
// Zero-fill d_out with wide stores. grid 2048 x 256, 8 float4 per thread.
// ---------------------------------------------------------------------------
__global__ __launch_bounds__(256)
void fill_zero(float4* __restrict__ out)
{
    const size_t i = (size_t)blockIdx.x * 256 + threadIdx.x;
    const float4 z = {0.f, 0.f, 0.f, 0.f};
    #pragma unroll
    for (int q = 0; q < 8; ++q)
        out[i + (size_t)q * 524288] = z;
}

// ---------------------------------------------------------------------------
// Pack f32 [M][K] -> bf16 (hi only), MFMA-ready layout:
// elem(row,k) -> offset ((((row>>6)*KC + (k>>6))*8 + ((k>>3)&7))*64 + (row&63))*8 + (k&7)
// gid covers (p,kc,kb,r); each thread writes 8 elems (16B). grid = M*K/2048.
// ---------------------------------------------------------------------------
__global__ __launch_bounds__(256)
void pack_bf16(const float* __restrict__ in, u16* __restrict__ hi, int K, int kcs)
{
    const int gid = blockIdx.x * 256 + threadIdx.x;
    const int r   = gid & 63;
    const int kb  = (gid >> 6) & 7;
    const int pkc = gid >> 9;
    const int kc  = pkc & ((1 << kcs) - 1);
    const int p   = pkc >> kcs;
    const size_t row = ((size_t)p << 6) | r;
    const int k0 = (kc << 6) | (kb << 3);

    const float* src = in + row * (size_t)K + k0;
    const float4 v0 = *(const float4*)src;
    const float4 v1 = *(const float4*)(src + 4);
    const float vv[8] = {v0.x, v0.y, v0.z, v0.w, v1.x, v1.y, v1.z, v1.w};

    u32 hw[4];
    #pragma unroll
    for (int q = 0; q < 4; ++q)
        hw[q] = (u32)f2bf(vv[2 * q]) | ((u32)f2bf(vv[2 * q + 1]) << 16);
    uint4 hv = {hw[0], hw[1], hw[2], hw[3]};
    *(uint4*)(hi + (size_t)gid * 8) = hv;
}

// ---------------------------------------------------------------------------
// Wab[r][c] (512x256): r<256 -> (We1a@W2)[r,c], r>=256 -> (We1b@W2)[r-256,c].
// Emits packed bf16 directly (W-operand layout, K=256, KC=4).
// grid 64 x 256; block handles 8 consecutive r.
// ---------------------------------------------------------------------------
__global__ __launch_bounds__(256)
void fold_wab(const float* __restrict__ We1, const float* __restrict__ W2,
              u16* __restrict__ wabh)
{
    const int r0 = blockIdx.x * 8;
    const int c  = threadIdx.x;
    float acc[8] = {};
    for (int k = 0; k < 256; ++k) {
        const float w2 = W2[k * 256 + c];
        #pragma unroll
        for (int j = 0; j < 8; ++j) {
            const int r = r0 + j;
            const int i = r & 255;
            const int koff = (r >> 8) << 8;
            acc[j] += We1[(size_t)i * 512 + koff + k] * w2;
        }
    }
    const int kc = c >> 6, kb = (c >> 3) & 7, e = c & 7;
    #pragma unroll
    for (int j = 0; j < 8; ++j) {
        const int r = r0 + j;
        wabh[(((((size_t)(r >> 6) << 2) + kc) << 3) + kb) * 512 + (size_t)(r & 63) * 8 + e]
            = f2bf(acc[j]);
    }
}

// bab[r] = (r<256 ? be1[r] : 0) + dot(We1 row-part, b2); grid 2 x 256
__global__ __launch_bounds__(256)
void fold_bab(const float* __restrict__ We1, const float* __restrict__ b2,
              const float* __restrict__ be1, float* __restrict__ bab)
{
    const int r = blockIdx.x * 256 + threadIdx.x;
    const int i = r & 255;
    const int koff = (r >> 8) << 8;
    float acc = (r < 256) ? be1[i] : 0.0f;
    for (int k = 0; k < 256; k += 4) {
        const float4 w = *(const float4*)(We1 + (size_t)i * 512 + koff + k);
        const float4 b = *(const float4*)(b2 + k);
        acc += w.x * b.x + w.y * b.y + w.z * b.z + w.w * b.w;
    }
    bab[r] = acc;
}

// ---------------------------------------------------------------------------
// bf16 MFMA GEMM: C = act(A @ W.T + bias), A/W pre-packed bf16.
// 64x64 tile, BK=64, 4 waves, 16x16x32 MFMA, dbuf LDS via global_load_lds(16B).
// grid = (M/64, Nout/64); KC = K/64.
// CMODE 1: C bf16 row-major [M][Nout].  CMODE 2: C packed bf16 A-operand
// layout for a next GEMM with KCnext = Nout/64.
// ---------------------------------------------------------------------------
template<int CMODE>
__global__ __launch_bounds__(256)
void mfma_gemm(const u16* __restrict__ A, const u16* __restrict__ W,
               const float* __restrict__ bias, u16* __restrict__ Cout,
               int Nout, int KC, int relu, int KCnext)
{
    __shared__ u16 As[2][4096];
    __shared__ u16 Bs[2][4096];
    const int tid  = threadIdx.x;
    const int wv   = tid >> 6;
    const int lane = tid & 63;
    const int bp   = blockIdx.x;
    const int bn   = blockIdx.y;

    auto stage = [&](int b, int t) {
        const u16* ga = A + (((size_t)bp * KC + t) << 12);
        const u16* gw = W + (((size_t)bn * KC + t) << 12);
        #pragma unroll
        for (int c = 0; c < 2; ++c) {
            const int ch = (wv << 1) + c;
            __builtin_amdgcn_global_load_lds(
                (const AS1 u32*)(ga + (ch << 9) + (lane << 3)),
                (AS3 u32*)(&As[b][ch << 9]), 16, 0, 0);
            __builtin_amdgcn_global_load_lds(
                (const AS1 u32*)(gw + (ch << 9) + (lane << 3)),
                (AS3 u32*)(&Bs[b][ch << 9]), 16, 0, 0);
        }
    };

    f32x4 acc[4];
    #pragma unroll
    for (int m = 0; m < 4; ++m) acc[m] = (f32x4){0.f, 0.f, 0.f, 0.f};

    const int kq  = lane >> 4;
    const int r16 = lane & 15;

    auto compute = [&](int b) {
        #pragma unroll
        for (int s = 0; s < 2; ++s) {
            const int kb = (s << 2) + kq;
            const bf16x8 bf = *(const bf16x8*)&Bs[b][((kb << 6) + (wv << 4) + r16) << 3];
            #pragma unroll
            for (int m = 0; m < 4; ++m) {
                const bf16x8 af = *(const bf16x8*)&As[b][((kb << 6) + (m << 4) + r16) << 3];
                acc[m] = __builtin_amdgcn_mfma_f32_16x16x32_bf16(af, bf, acc[m], 0, 0, 0);
            }
        }
    };

    stage(0, 0);
    __syncthreads();
    int buf = 0;
    for (int t = 0; t < KC; ++t) {
        if (t + 1 < KC) stage(buf ^ 1, t + 1);
        compute(buf);
        __syncthreads();
        buf ^= 1;
    }

    // C/D layout: col = lane&15, row = (lane>>4)*4 + j
    const int col  = (bn << 6) + (wv << 4) + r16;
    const float bv = bias[col];
    if constexpr (CMODE == 1) {
        #pragma unroll
        for (int m = 0; m < 4; ++m)
            #pragma unroll
            for (int j = 0; j < 4; ++j) {
                float v = acc[m][j] + bv;
                if (relu) v = fmaxf(v, 0.0f);
                const int row = (bp << 6) + (kq << 2) + (m << 4) + j;
                Cout[(size_t)row * Nout + col] = f2bf(v);
            }
    } else {
        const int kb2 = (wv << 1) | (r16 >> 3);
        const int e2  = r16 & 7;
        u16* Cp = Cout + (((((size_t)bp * KCnext + bn) << 3) + kb2) << 9) + e2;
        #pragma unroll
        for (int m = 0; m < 4; ++m)
            #pragma unroll
            for (int j = 0; j < 4; ++j) {
                float v = acc[m][j] + bv;
                if (relu) v = fmaxf(v, 0.0f);
                Cp[(size_t)((kq << 2) + (m << 4) + j) << 3] = f2bf(v);
            }
    }
}

// ---------------------------------------------------------------------------
// Edge MLP (bf16 AB): one wave per edge, lane l holds channels [4l,4l+3].
// s[e] = dot(relu(AB[src,0:256] + AB[dst,256:512]), We2) + be2
// Fused per-block max -> part[blockIdx.x].
// ---------------------------------------------------------------------------
__global__ __launch_bounds__(256)
void edge_mlp(const u16* __restrict__ AB, const int* __restrict__ idx,
              const float* __restrict__ We2, const float* __restrict__ be2p,
              float* __restrict__ s, float* __restrict__ part, int n)
{
    __shared__ float sm[256];
    const int gtid = blockIdx.x * blockDim.x + threadIdx.x;
    const int wave = gtid >> 6;
    const int lane = threadIdx.x & 63;
    const int nwaves = (gridDim.x * blockDim.x) >> 6;
    const float4 w2 = ((const float4*)We2)[lane];
    const float be2 = be2p[0];
    float mloc = -3.0e38f;

    for (int e = wave; e < n; e += nwaves) {
        const int src = idx[2 * e];
        const int dst = idx[2 * e + 1];
        const ushort4 a = *(const ushort4*)(AB + ((size_t)src << 9) + (lane << 2));
        const ushort4 b = *(const ushort4*)(AB + ((size_t)dst << 9) + 256 + (lane << 2));
        float p = fmaxf(bf2f(a.x) + bf2f(b.x), 0.0f) * w2.x
                + fmaxf(bf2f(a.y) + bf2f(b.y), 0.0f) * w2.y
                + fmaxf(bf2f(a.z) + bf2f(b.z), 0.0f) * w2.z
                + fmaxf(bf2f(a.w) + bf2f(b.w), 0.0f) * w2.w;
        #pragma unroll
        for (int m = 32; m > 0; m >>= 1)
            p += __shfl_xor(p, m, 64);
        p += be2;
        if (lane == 0) s[e] = p;
        mloc = fmaxf(mloc, p);
    }
    sm[threadIdx.x] = mloc;
    __syncthreads();
    for (int st = 128; st > 0; st >>= 1) {
        if (threadIdx.x < st) sm[threadIdx.x] = fmaxf(sm[threadIdx.x], sm[threadIdx.x + st]);
        __syncthreads();
    }
    if (threadIdx.x == 0) part[blockIdx.x] = sm[0];
}

// fused: finalize max over part[1024] (redundant per block) + partial sumexp
__global__ __launch_bounds__(256)
void sumexp_part(const float* __restrict__ s, const float* __restrict__ part,
                 int n, float* __restrict__ part2, float* __restrict__ g)
{
    __shared__ float sm[256];
    float m = part[threadIdx.x];
    m = fmaxf(m, part[threadIdx.x + 256]);
    m = fmaxf(m, part[threadIdx.x + 512]);
    m = fmaxf(m, part[threadIdx.x + 768]);
    sm[threadIdx.x] = m;
    __syncthreads();
    for (int st = 128; st > 0; st >>= 1) {
        if (threadIdx.x < st) sm[threadIdx.x] = fmaxf(sm[threadIdx.x], sm[threadIdx.x + st]);
        __syncthreads();
    }
    const float gm = sm[0];
    __syncthreads();
    float a = 0.0f;
    for (int i = blockIdx.x * 256 + threadIdx.x; i < n; i += 256 * gridDim.x)
        a += expf(s[i] - gm);
    sm[threadIdx.x] = a;
    __syncthreads();
    for (int st = 128; st > 0; st >>= 1) {
        if (threadIdx.x < st) sm[threadIdx.x] += sm[threadIdx.x + st];
        __syncthreads();
    }
    if (threadIdx.x == 0) {
        part2[blockIdx.x] = sm[0];
        if (blockIdx.x == 0) g[0] = gm;
    }
}

// fused: finalize sum (redundant per block) + scatter probs
__global__ __launch_bounds__(256)
void scatter_probs(const float* __restrict__ s, const int* __restrict__ idx,
                   const float* __restrict__ part2, const float* __restrict__ g,
                   float* __restrict__ out, int n)
{
    __shared__ float sm[256];
    sm[threadIdx.x] = part2[threadIdx.x];
    __syncthreads();
    for (int st = 128; st > 0; st >>= 1) {
        if (threadIdx.x < st) sm[threadIdx.x] += sm[threadIdx.x + st];
        __syncthreads();
    }
    const float Z = sm[0];
    const float gm = g[0];
    const int e = blockIdx.x * 256 + threadIdx.x;
    if (e < n)
        out[(size_t)idx[2 * e] * N_NODES + idx[2 * e + 1]] = expf(s[e] - gm) / Z;
}

// ---------------------------------------------------------------------------
extern "C" void kernel_launch(void* const* d_in, const int* in_sizes, int n_in,
                              void* d_out, int out_size, void* d_ws, size_t ws_size,
                              hipStream_t stream)
{
    const float* ideal = (const float*)d_in[0];   // 4096 x 1024
    const int*   idx   = (const int*)d_in[1];     // E x 2
    const float* W1    = (const float*)d_in[2];   // 256 x 1024
    const float* b1    = (const float*)d_in[3];   // 256
    const float* W2    = (const float*)d_in[4];   // 256 x 256
    const float* b2    = (const float*)d_in[5];   // 256
    const float* We1   = (const float*)d_in[6];   // 256 x 512
    const float* be1   = (const float*)d_in[7];   // 256
    const float* We2   = (const float*)d_in[8];   // 256
    const float* be2   = (const float*)d_in[9];   // 1
    float* out = (float*)d_out;

    // workspace (byte offsets):
    //   [0,8M):        xh packed (4096x1024 bf16)
    //   [8M,8.5M):     w1h packed
    //   [8.5M,8.75M):  wabh packed
    //   [9M,11M):      h1h packed (4096x256 bf16)
    //   [11M,+2KB):    bab f32[512]
    //   [12M,16M):     ABbf row-major bf16 (4096x512)
    //   [16M,16.5M):   sbuf f32[E]
    //   then part[1024], part2[256], g[1]
    char* Wb = (char*)d_ws;
    u16*   xh   = (u16*)(Wb);
    u16*   w1h  = (u16*)(Wb + (8u << 20));
    u16*   wabh = (u16*)(Wb + (8u << 20) + (512u << 10));
    u16*   h1h  = (u16*)(Wb + (9u << 20));
    float* bab  = (float*)(Wb + (11u << 20));
    u16*   ABbf = (u16*)(Wb + (12u << 20));
    float* sbuf = (float*)(Wb + (16u << 20));
    float* part = sbuf + E_EDGES;
    float* part2 = part + 1024;
    float* g    = part2 + 256;

    pack_bf16<<<2048, 256, 0, stream>>>(ideal, xh, 1024, 4);
    pack_bf16<<<128, 256, 0, stream>>>(W1, w1h, 1024, 4);
    fold_wab<<<64, 256, 0, stream>>>(We1, W2, wabh);
    fold_bab<<<2, 256, 0, stream>>>(We1, b2, be1, bab);

    // h1 packed = relu(x @ W1.T + b1)
    mfma_gemm<2><<<dim3(64, 4), 256, 0, stream>>>(xh, w1h, b1, h1h, 256, 16, 1, 4);
    // AB bf16 = h1 @ Wab.T + bab   (N = 512: [A | B])
    mfma_gemm<1><<<dim3(64, 8), 256, 0, stream>>>(h1h, wabh, bab, ABbf, 512, 4, 0, 0);

    fill_zero<<<2048, 256, 0, stream>>>((float4*)out);

    edge_mlp<<<1024, 256, 0, stream>>>(ABbf, idx, We2, be2, sbuf, part, E_EDGES);
    sumexp_part<<<256, 256, 0, stream>>>(sbuf, part, E_EDGES, part2, g);
    scatter_probs<<<512, 256, 0, stream>>>(sbuf, idx, part2, g, out, E_EDGES);
}

// Round 6
// 80.398 us; speedup vs baseline: 1.9650x; 1.3563x over previous
//
#include <hip/hip_runtime.h>
#include <hip/hip_bf16.h>

// TwinPolicy, pure-bf16 MFMA pipeline:
//   h1p = pack(relu(x @ W1.T + b1))               (bf16 MFMA GEMM, K=1024, packed epilogue)
//   ABbf = bf16(h1 @ [We1a@W2 ; We1b@W2].T + bab) (bf16 MFMA GEMM, N=512, bf16 row-major out)
//   s[e] = dot(relu(AB[src,:256] + AB[dst,256:]), We2) + be2   (half-wave per edge)
//   out = softmax over 4096x4096 grid (finite only at E edge slots)

typedef unsigned short u16;
typedef unsigned int   u32;
typedef __attribute__((ext_vector_type(8))) short bf16x8;
typedef __attribute__((ext_vector_type(4))) float f32x4;

#define N_NODES 4096
#define E_EDGES 131072
#define AS1 __attribute__((address_space(1)))
#define AS3 __attribute__((address_space(3)))

__device__ __forceinline__ u16 f2bf(float f) {
    u32 u = __float_as_uint(f);
    return (u16)((u + 0x7FFFu + ((u >> 16) & 1u)) >> 16);
}
__device__ __forceinline__ float bf2f(u16 h) {
    return __uint_as_float(((u32)h) << 16);
}
__device__ __forceinline__ float bflo(u32 w) { return __uint_as_float(w << 16); }
__device__ __forceinline__ float bfhi(u32 w) { return __uint_as_float(w & 0xffff0000u); }

// ---------------------------------------------------------------------------
// Zero-fill d_out. grid 2048 x 256, 8 float4 per thread.
// ---------------------------------------------------------------------------
__global__ __launch_bounds__(256)
void fill_zero(float4* __restrict__ out)
{
    const size_t i = (size_t)blockIdx.x * 256 + threadIdx.x;
    const float4 z = {0.f, 0.f, 0.f, 0.f};
    #pragma unroll
    for (int q = 0; q < 8; ++q)
        out[i + (size_t)q * 524288] = z;
}

// ---------------------------------------------------------------------------
// Pack f32 [M][K] -> bf16, MFMA-ready layout:
// elem(row,k) -> ((((row>>6)*KC + (k>>6))*8 + ((k>>3)&7))*64 + (row&63))*8 + (k&7)
// ---------------------------------------------------------------------------
__device__ __forceinline__ void pack_body(const float* __restrict__ in,
                                          u16* __restrict__ hi, int K, int kcs, int gid)
{
    const int r   = gid & 63;
    const int kb  = (gid >> 6) & 7;
    const int pkc = gid >> 9;
    const int kc  = pkc & ((1 << kcs) - 1);
    const int p   = pkc >> kcs;
    const size_t row = ((size_t)p << 6) | r;
    const int k0 = (kc << 6) | (kb << 3);

    const float* src = in + row * (size_t)K + k0;
    const float4 v0 = *(const float4*)src;
    const float4 v1 = *(const float4*)(src + 4);
    const float vv[8] = {v0.x, v0.y, v0.z, v0.w, v1.x, v1.y, v1.z, v1.w};

    u32 hw[4];
    #pragma unroll
    for (int q = 0; q < 4; ++q)
        hw[q] = (u32)f2bf(vv[2 * q]) | ((u32)f2bf(vv[2 * q + 1]) << 16);
    uint4 hv = {hw[0], hw[1], hw[2], hw[3]};
    *(uint4*)(hi + (size_t)gid * 8) = hv;
}

__global__ __launch_bounds__(256)
void pack_bf16(const float* __restrict__ in, u16* __restrict__ hi, int K, int kcs)
{
    pack_body(in, hi, K, kcs, blockIdx.x * 256 + threadIdx.x);
}

// ---------------------------------------------------------------------------
// Fused weight prep, partitioned by blockIdx:
//   [0,128):   pack W1 (256x1024) -> w1h
//   [128,192): Wab[r][c] = (r<256 ? We1a@W2 : We1b@W2), packed bf16 W-operand
//   [192,194): bab[r] = (r<256 ? be1[r] : 0) + dot(We1 row-part, b2)
// ---------------------------------------------------------------------------
__global__ __launch_bounds__(256)
void prep_weights(const float* __restrict__ W1, const float* __restrict__ We1,
                  const float* __restrict__ W2, const float* __restrict__ b2,
                  const float* __restrict__ be1,
                  u16* __restrict__ w1h, u16* __restrict__ wabh,
                  float* __restrict__ bab)
{
    const int bid = blockIdx.x;
    if (bid < 128) {
        pack_body(W1, w1h, 1024, 4, bid * 256 + threadIdx.x);
    } else if (bid < 192) {
        const int r0 = (bid - 128) * 8;
        const int c  = threadIdx.x;
        float acc[8] = {};
        for (int k = 0; k < 256; ++k) {
            const float w2 = W2[k * 256 + c];
            #pragma unroll
            for (int j = 0; j < 8; ++j) {
                const int r = r0 + j;
                acc[j] += We1[(size_t)(r & 255) * 512 + ((r >> 8) << 8) + k] * w2;
            }
        }
        const int kc = c >> 6, kb = (c >> 3) & 7, e = c & 7;
        #pragma unroll
        for (int j = 0; j < 8; ++j) {
            const int r = r0 + j;
            wabh[(((((size_t)(r >> 6) << 2) + kc) << 3) + kb) * 512 + (size_t)(r & 63) * 8 + e]
                = f2bf(acc[j]);
        }
    } else {
        const int r = (bid - 192) * 256 + threadIdx.x;
        const int i = r & 255;
        const int koff = (r >> 8) << 8;
        float acc = (r < 256) ? be1[i] : 0.0f;
        for (int k = 0; k < 256; k += 4) {
            const float4 w = *(const float4*)(We1 + (size_t)i * 512 + koff + k);
            const float4 b = *(const float4*)(b2 + k);
            acc += w.x * b.x + w.y * b.y + w.z * b.z + w.w * b.w;
        }
        bab[r] = acc;
    }
}

// ---------------------------------------------------------------------------
// bf16 MFMA GEMM: C = act(A @ W.T + bias), A/W pre-packed bf16.
// 64x64 tile, BK=64, 4 waves, 16x16x32 MFMA, dbuf LDS via global_load_lds(16B).
// CMODE 1: C bf16 row-major. CMODE 2: C packed bf16 A-operand layout (KCnext).
// ---------------------------------------------------------------------------
template<int CMODE>
__global__ __launch_bounds__(256)
void mfma_gemm(const u16* __restrict__ A, const u16* __restrict__ W,
               const float* __restrict__ bias, u16* __restrict__ Cout,
               int Nout, int KC, int relu, int KCnext)
{
    __shared__ u16 As[2][4096];
    __shared__ u16 Bs[2][4096];
    const int tid  = threadIdx.x;
    const int wv   = tid >> 6;
    const int lane = tid & 63;
    const int bp   = blockIdx.x;
    const int bn   = blockIdx.y;

    auto stage = [&](int b, int t) {
        const u16* ga = A + (((size_t)bp * KC + t) << 12);
        const u16* gw = W + (((size_t)bn * KC + t) << 12);
        #pragma unroll
        for (int c = 0; c < 2; ++c) {
            const int ch = (wv << 1) + c;
            __builtin_amdgcn_global_load_lds(
                (const AS1 u32*)(ga + (ch << 9) + (lane << 3)),
                (AS3 u32*)(&As[b][ch << 9]), 16, 0, 0);
            __builtin_amdgcn_global_load_lds(
                (const AS1 u32*)(gw + (ch << 9) + (lane << 3)),
                (AS3 u32*)(&Bs[b][ch << 9]), 16, 0, 0);
        }
    };

    f32x4 acc[4];
    #pragma unroll
    for (int m = 0; m < 4; ++m) acc[m] = (f32x4){0.f, 0.f, 0.f, 0.f};

    const int kq  = lane >> 4;
    const int r16 = lane & 15;

    auto compute = [&](int b) {
        #pragma unroll
        for (int s = 0; s < 2; ++s) {
            const int kb = (s << 2) + kq;
            const bf16x8 bf = *(const bf16x8*)&Bs[b][((kb << 6) + (wv << 4) + r16) << 3];
            #pragma unroll
            for (int m = 0; m < 4; ++m) {
                const bf16x8 af = *(const bf16x8*)&As[b][((kb << 6) + (m << 4) + r16) << 3];
                acc[m] = __builtin_amdgcn_mfma_f32_16x16x32_bf16(af, bf, acc[m], 0, 0, 0);
            }
        }
    };

    stage(0, 0);
    __syncthreads();
    int buf = 0;
    for (int t = 0; t < KC; ++t) {
        if (t + 1 < KC) stage(buf ^ 1, t + 1);
        compute(buf);
        __syncthreads();
        buf ^= 1;
    }

    const int col  = (bn << 6) + (wv << 4) + r16;   // C/D: col=lane&15, row=(lane>>4)*4+j
    const float bv = bias[col];
    if constexpr (CMODE == 1) {
        #pragma unroll
        for (int m = 0; m < 4; ++m)
            #pragma unroll
            for (int j = 0; j < 4; ++j) {
                float v = acc[m][j] + bv;
                if (relu) v = fmaxf(v, 0.0f);
                const int row = (bp << 6) + (kq << 2) + (m << 4) + j;
                Cout[(size_t)row * Nout + col] = f2bf(v);
            }
    } else {
        const int kb2 = (wv << 1) | (r16 >> 3);
        const int e2  = r16 & 7;
        u16* Cp = Cout + (((((size_t)bp * KCnext + bn) << 3) + kb2) << 9) + e2;
        #pragma unroll
        for (int m = 0; m < 4; ++m)
            #pragma unroll
            for (int j = 0; j < 4; ++j) {
                float v = acc[m][j] + bv;
                if (relu) v = fmaxf(v, 0.0f);
                Cp[(size_t)((kq << 2) + (m << 4) + j) << 3] = f2bf(v);
            }
    }
}

// ---------------------------------------------------------------------------
// Edge MLP: HALF-WAVE (32 lanes) per edge, 8 channels/lane via one uint4 load.
// grid 2048 x 256 = 8192 waves -> 16384 edges per sweep, 8 unrolled sweeps
// (8192 waves * 2 edges * 8 = 131072 = E).  Fused per-block max.
// ---------------------------------------------------------------------------
__global__ __launch_bounds__(256)
void edge_mlp(const u16* __restrict__ AB, const int* __restrict__ idx,
              const float* __restrict__ We2, const float* __restrict__ be2p,
              float* __restrict__ s, float* __restrict__ part)
{
    __shared__ float sm[256];
    const int tid  = threadIdx.x;
    const int lane = tid & 63;
    const int sub  = lane >> 5;          // which edge of the wave's pair
    const int l5   = lane & 31;          // channel group: ch [8*l5, 8*l5+7]
    const int wid  = (blockIdx.x * 256 + tid) >> 6;     // 0..8191
    const float be2 = be2p[0];

    float w2v[8];
    #pragma unroll
    for (int q = 0; q < 2; ++q) {
        const float4 w = ((const float4*)We2)[l5 * 2 + q];
        w2v[q * 4 + 0] = w.x; w2v[q * 4 + 1] = w.y;
        w2v[q * 4 + 2] = w.z; w2v[q * 4 + 3] = w.w;
    }

    float mloc = -3.0e38f;
    #pragma unroll
    for (int it = 0; it < 8; ++it) {
        const int e = (wid << 1) + sub + (it << 14);    // + it*16384, covers [0, 131072)
        const int src = idx[2 * e];
        const int dst = idx[2 * e + 1];
        const uint4 av = *(const uint4*)(AB + ((size_t)src << 9) + (l5 << 3));
        const uint4 bv = *(const uint4*)(AB + ((size_t)dst << 9) + 256 + (l5 << 3));
        const u32 aw[4] = {av.x, av.y, av.z, av.w};
        const u32 bw[4] = {bv.x, bv.y, bv.z, bv.w};
        float p = 0.0f;
        #pragma unroll
        for (int q = 0; q < 4; ++q) {
            p += fmaxf(bflo(aw[q]) + bflo(bw[q]), 0.0f) * w2v[2 * q];
            p += fmaxf(bfhi(aw[q]) + bfhi(bw[q]), 0.0f) * w2v[2 * q + 1];
        }
        #pragma unroll
        for (int m = 16; m > 0; m >>= 1)
            p += __shfl_xor(p, m, 64);   // xor<32: stays within the half-wave
        p += be2;
        if (l5 == 0) s[e] = p;
        mloc = fmaxf(mloc, p);
    }
    sm[tid] = mloc;
    __syncthreads();
    for (int st = 128; st > 0; st >>= 1) {
        if (tid < st) sm[tid] = fmaxf(sm[tid], sm[tid + st]);
        __syncthreads();
    }
    if (tid == 0) part[blockIdx.x] = sm[0];
}

// fused: finalize max over part[2048] (redundant per block) + partial sumexp
__global__ __launch_bounds__(256)
void sumexp_part(const float* __restrict__ s, const float* __restrict__ part,
                 int n, float* __restrict__ part2, float* __restrict__ g)
{
    __shared__ float sm[256];
    float m = part[threadIdx.x];
    #pragma unroll
    for (int k = 1; k < 8; ++k)
        m = fmaxf(m, part[threadIdx.x + k * 256]);
    sm[threadIdx.x] = m;
    __syncthreads();
    for (int st = 128; st > 0; st >>= 1) {
        if (threadIdx.x < st) sm[threadIdx.x] = fmaxf(sm[threadIdx.x], sm[threadIdx.x + st]);
        __syncthreads();
    }
    const float gm = sm[0];
    __syncthreads();
    float a = 0.0f;
    for (int i = blockIdx.x * 256 + threadIdx.x; i < n; i += 256 * gridDim.x)
        a += expf(s[i] - gm);
    sm[threadIdx.x] = a;
    __syncthreads();
    for (int st = 128; st > 0; st >>= 1) {
        if (threadIdx.x < st) sm[threadIdx.x] += sm[threadIdx.x + st];
        __syncthreads();
    }
    if (threadIdx.x == 0) {
        part2[blockIdx.x] = sm[0];
        if (blockIdx.x == 0) g[0] = gm;
    }
}

// fused: finalize sum (redundant per block) + scatter probs
__global__ __launch_bounds__(256)
void scatter_probs(const float* __restrict__ s, const int* __restrict__ idx,
                   const float* __restrict__ part2, const float* __restrict__ g,
                   float* __restrict__ out, int n)
{
    __shared__ float sm[256];
    sm[threadIdx.x] = part2[threadIdx.x];
    __syncthreads();
    for (int st = 128; st > 0; st >>= 1) {
        if (threadIdx.x < st) sm[threadIdx.x] += sm[threadIdx.x + st];
        __syncthreads();
    }
    const float Z = sm[0];
    const float gm = g[0];
    const int e = blockIdx.x * 256 + threadIdx.x;
    if (e < n)
        out[(size_t)idx[2 * e] * N_NODES + idx[2 * e + 1]] = expf(s[e] - gm) / Z;
}

// ---------------------------------------------------------------------------
extern "C" void kernel_launch(void* const* d_in, const int* in_sizes, int n_in,
                              void* d_out, int out_size, void* d_ws, size_t ws_size,
                              hipStream_t stream)
{
    const float* ideal = (const float*)d_in[0];   // 4096 x 1024
    const int*   idx   = (const int*)d_in[1];     // E x 2
    const float* W1    = (const float*)d_in[2];   // 256 x 1024
    const float* b1    = (const float*)d_in[3];   // 256
    const float* W2    = (const float*)d_in[4];   // 256 x 256
    const float* b2    = (const float*)d_in[5];   // 256
    const float* We1   = (const float*)d_in[6];   // 256 x 512
    const float* be1   = (const float*)d_in[7];   // 256
    const float* We2   = (const float*)d_in[8];   // 256
    const float* be2   = (const float*)d_in[9];   // 1
    float* out = (float*)d_out;

    char* Wb = (char*)d_ws;
    u16*   xh   = (u16*)(Wb);                          // 8 MB packed x
    u16*   w1h  = (u16*)(Wb + (8u << 20));             // 512 KB packed W1
    u16*   wabh = (u16*)(Wb + (8u << 20) + (512u << 10)); // 256 KB packed Wab
    u16*   h1h  = (u16*)(Wb + (9u << 20));             // 2 MB packed h1
    float* bab  = (float*)(Wb + (11u << 20));          // 2 KB
    u16*   ABbf = (u16*)(Wb + (12u << 20));            // 4 MB bf16 AB row-major
    float* sbuf = (float*)(Wb + (16u << 20));          // 512 KB scores
    float* part = sbuf + E_EDGES;                      // 2048
    float* part2 = part + 2048;                        // 256
    float* g    = part2 + 256;                         // 1

    pack_bf16<<<2048, 256, 0, stream>>>(ideal, xh, 1024, 4);
    prep_weights<<<194, 256, 0, stream>>>(W1, We1, W2, b2, be1, w1h, wabh, bab);

    // h1 packed = relu(x @ W1.T + b1)
    mfma_gemm<2><<<dim3(64, 4), 256, 0, stream>>>(xh, w1h, b1, h1h, 256, 16, 1, 4);
    // AB bf16 = h1 @ Wab.T + bab   (N = 512: [A | B])
    mfma_gemm<1><<<dim3(64, 8), 256, 0, stream>>>(h1h, wabh, bab, ABbf, 512, 4, 0, 0);

    fill_zero<<<2048, 256, 0, stream>>>((float4*)out);

    edge_mlp<<<2048, 256, 0, stream>>>(ABbf, idx, We2, be2, sbuf, part);
    sumexp_part<<<256, 256, 0, stream>>>(sbuf, part, E_EDGES, part2, g);
    scatter_probs<<<512, 256, 0, stream>>>(sbuf, idx, part2, g, out, E_EDGES);
}

// Round 7
// 79.466 us; speedup vs baseline: 1.9880x; 1.0117x over previous
//
#include <hip/hip_runtime.h>
#include <hip/hip_bf16.h>

// TwinPolicy, pure-bf16 MFMA pipeline (6 launches):
//   prep_all: pack x -> xh, pack W1 -> w1h, fold Wab=(We1@W2) -> wabh, bab
//   h1p = pack(relu(x @ W1.T + b1))     gemm1: BM=32 BN=64, 512 blocks (2/CU)
//   ABbf = bf16(h1 @ Wab.T + bab)       gemm2: 64x64, 512 blocks
//   edge_mlp_fill: s[e] = dot(relu(AB[src,:256]+AB[dst,256:]),We2)+be2
//                  + zero-fill of the 67MB output (overlaps gather latency)
//   sumexp_part / scatter_probs: global softmax + scatter

typedef unsigned short u16;
typedef unsigned int   u32;
typedef __attribute__((ext_vector_type(8))) short bf16x8;
typedef __attribute__((ext_vector_type(4))) float f32x4;

#define N_NODES 4096
#define E_EDGES 131072
#define AS1 __attribute__((address_space(1)))
#define AS3 __attribute__((address_space(3)))

__device__ __forceinline__ u16 f2bf(float f) {
    u32 u = __float_as_uint(f);
    return (u16)((u + 0x7FFFu + ((u >> 16) & 1u)) >> 16);
}
__device__ __forceinline__ float bflo(u32 w) { return __uint_as_float(w << 16); }
__device__ __forceinline__ float bfhi(u32 w) { return __uint_as_float(w & 0xffff0000u); }

// ---------------------------------------------------------------------------
// Pack f32 [M][K] -> bf16, MFMA-ready layout:
// elem(row,k) -> ((((row>>6)*KC + (k>>6))*8 + ((k>>3)&7))*64 + (row&63))*8 + (k&7)
// ---------------------------------------------------------------------------
__device__ __forceinline__ void pack_body(const float* __restrict__ in,
                                          u16* __restrict__ hi, int K, int kcs, int gid)
{
    const int r   = gid & 63;
    const int kb  = (gid >> 6) & 7;
    const int pkc = gid >> 9;
    const int kc  = pkc & ((1 << kcs) - 1);
    const int p   = pkc >> kcs;
    const size_t row = ((size_t)p << 6) | r;
    const int k0 = (kc << 6) | (kb << 3);

    const float* src = in + row * (size_t)K + k0;
    const float4 v0 = *(const float4*)src;
    const float4 v1 = *(const float4*)(src + 4);
    const float vv[8] = {v0.x, v0.y, v0.z, v0.w, v1.x, v1.y, v1.z, v1.w};

    u32 hw[4];
    #pragma unroll
    for (int q = 0; q < 4; ++q)
        hw[q] = (u32)f2bf(vv[2 * q]) | ((u32)f2bf(vv[2 * q + 1]) << 16);
    uint4 hv = {hw[0], hw[1], hw[2], hw[3]};
    *(uint4*)(hi + (size_t)gid * 8) = hv;
}

// ---------------------------------------------------------------------------
// Fused prep, partitioned by blockIdx (2242 blocks):
//   [0,2048):     pack ideal (4096x1024) -> xh
//   [2048,2176):  pack W1 (256x1024) -> w1h
//   [2176,2240):  Wab[r][c] = (r<256 ? We1a@W2 : We1b@W2), packed bf16 W-layout
//   [2240,2242):  bab[r] = (r<256 ? be1[r] : 0) + dot(We1 row-part, b2)
// ---------------------------------------------------------------------------
__global__ __launch_bounds__(256)
void prep_all(const float* __restrict__ ideal, const float* __restrict__ W1,
              const float* __restrict__ We1, const float* __restrict__ W2,
              const float* __restrict__ b2, const float* __restrict__ be1,
              u16* __restrict__ xh, u16* __restrict__ w1h,
              u16* __restrict__ wabh, float* __restrict__ bab)
{
    const int bid = blockIdx.x;
    if (bid < 2048) {
        pack_body(ideal, xh, 1024, 4, bid * 256 + threadIdx.x);
    } else if (bid < 2176) {
        pack_body(W1, w1h, 1024, 4, (bid - 2048) * 256 + threadIdx.x);
    } else if (bid < 2240) {
        const int r0 = (bid - 2176) * 8;
        const int c  = threadIdx.x;
        float acc[8] = {};
        for (int k = 0; k < 256; ++k) {
            const float w2 = W2[k * 256 + c];
            #pragma unroll
            for (int j = 0; j < 8; ++j) {
                const int r = r0 + j;
                acc[j] += We1[(size_t)(r & 255) * 512 + ((r >> 8) << 8) + k] * w2;
            }
        }
        const int kc = c >> 6, kb = (c >> 3) & 7, e = c & 7;
        #pragma unroll
        for (int j = 0; j < 8; ++j) {
            const int r = r0 + j;
            wabh[(((((size_t)(r >> 6) << 2) + kc) << 3) + kb) * 512 + (size_t)(r & 63) * 8 + e]
                = f2bf(acc[j]);
        }
    } else {
        const int r = (bid - 2240) * 256 + threadIdx.x;
        const int i = r & 255;
        const int koff = (r >> 8) << 8;
        float acc = (r < 256) ? be1[i] : 0.0f;
        for (int k = 0; k < 256; k += 4) {
            const float4 w = *(const float4*)(We1 + (size_t)i * 512 + koff + k);
            const float4 b = *(const float4*)(b2 + k);
            acc += w.x * b.x + w.y * b.y + w.z * b.z + w.w * b.w;
        }
        bab[r] = acc;
    }
}

// ---------------------------------------------------------------------------
// GEMM1: h1p = relu(x @ W1.T + b1), packed epilogue for gemm2 (KCnext=4).
// BM=32, BN=64, KC=16, 4 waves, grid (128,4) = 512 blocks -> 2 blocks/CU.
// LDS: As 2x4KB [kb][32r][8e], Bs 2x8KB [kb][64c][8e].
// ---------------------------------------------------------------------------
__global__ __launch_bounds__(256)
void mfma_gemm1(const u16* __restrict__ A, const u16* __restrict__ W,
                const float* __restrict__ bias, u16* __restrict__ Cout)
{
    __shared__ u16 As[2][2048];
    __shared__ u16 Bs[2][4096];
    const int tid  = threadIdx.x;
    const int wv   = tid >> 6;
    const int lane = tid & 63;
    const int bp   = blockIdx.x;          // 0..127: 32-row block
    const int bn   = blockIdx.y;          // 0..3:   64-col panel
    const int p    = bp >> 1;
    const int r0   = (bp & 1) << 5;
    const int KC   = 16;

    auto stage = [&](int b, int t) {
        // A: 4KB, one 16B per thread; LDS dest = tid*16 (wave-uniform base + lane*16)
        {
            const int kb = tid >> 5, r = tid & 31;
            const u16* ga = A + (((((size_t)p * KC + t) << 3) + kb) << 9) + (size_t)(r0 + r) * 8;
            __builtin_amdgcn_global_load_lds((const AS1 u32*)ga,
                (AS3 u32*)(&As[b][tid << 3]), 16, 0, 0);
        }
        // W: 8KB, two 16B per thread
        const u16* gw = W + (((size_t)bn * KC + t) << 12);
        #pragma unroll
        for (int c = 0; c < 2; ++c) {
            const int ch = (wv << 1) + c;
            __builtin_amdgcn_global_load_lds(
                (const AS1 u32*)(gw + (ch << 9) + (lane << 3)),
                (AS3 u32*)(&Bs[b][ch << 9]), 16, 0, 0);
        }
    };

    f32x4 acc[2];
    #pragma unroll
    for (int m = 0; m < 2; ++m) acc[m] = (f32x4){0.f, 0.f, 0.f, 0.f};

    const int kq  = lane >> 4;
    const int r16 = lane & 15;

    auto compute = [&](int b) {
        #pragma unroll
        for (int s = 0; s < 2; ++s) {
            const int kb = (s << 2) + kq;
            const bf16x8 bf = *(const bf16x8*)&Bs[b][((kb << 6) + (wv << 4) + r16) << 3];
            #pragma unroll
            for (int m = 0; m < 2; ++m) {
                const bf16x8 af = *(const bf16x8*)&As[b][((kb << 5) + (m << 4) + r16) << 3];
                acc[m] = __builtin_amdgcn_mfma_f32_16x16x32_bf16(af, bf, acc[m], 0, 0, 0);
            }
        }
    };

    stage(0, 0);
    __syncthreads();
    int buf = 0;
    for (int t = 0; t < KC; ++t) {
        if (t + 1 < KC) stage(buf ^ 1, t + 1);
        compute(buf);
        __syncthreads();
        buf ^= 1;
    }

    // C/D: col=lane&15, row=(lane>>4)*4+j.  Packed A-layout epilogue (KCnext=4).
    const int col  = (bn << 6) + (wv << 4) + r16;
    const float bv = bias[col];
    const int kb2  = (wv << 1) | (r16 >> 3);
    const int e2   = r16 & 7;
    u16* Cp = Cout + (((((size_t)p * 4 + bn) << 3) + kb2) << 9) + e2;
    #pragma unroll
    for (int m = 0; m < 2; ++m)
        #pragma unroll
        for (int j = 0; j < 4; ++j) {
            const float v = fmaxf(acc[m][j] + bv, 0.0f);
            const int r64 = r0 + (kq << 2) + (m << 4) + j;
            Cp[(size_t)r64 << 3] = f2bf(v);
        }
}

// ---------------------------------------------------------------------------
// GEMM2: AB = h1 @ Wab.T + bab, bf16 row-major out.
// 64x64 tile, KC=4, 4 waves, grid (64,8) = 512 blocks.
// ---------------------------------------------------------------------------
__global__ __launch_bounds__(256)
void mfma_gemm2(const u16* __restrict__ A, const u16* __restrict__ W,
                const float* __restrict__ bias, u16* __restrict__ Cout)
{
    __shared__ u16 As[2][4096];
    __shared__ u16 Bs[2][4096];
    const int tid  = threadIdx.x;
    const int wv   = tid >> 6;
    const int lane = tid & 63;
    const int bp   = blockIdx.x;
    const int bn   = blockIdx.y;
    const int KC   = 4;
    const int Nout = 512;

    auto stage = [&](int b, int t) {
        const u16* ga = A + (((size_t)bp * KC + t) << 12);
        const u16* gw = W + (((size_t)bn * KC + t) << 12);
        #pragma unroll
        for (int c = 0; c < 2; ++c) {
            const int ch = (wv << 1) + c;
            __builtin_amdgcn_global_load_lds(
                (const AS1 u32*)(ga + (ch << 9) + (lane << 3)),
                (AS3 u32*)(&As[b][ch << 9]), 16, 0, 0);
            __builtin_amdgcn_global_load_lds(
                (const AS1 u32*)(gw + (ch << 9) + (lane << 3)),
                (AS3 u32*)(&Bs[b][ch << 9]), 16, 0, 0);
        }
    };

    f32x4 acc[4];
    #pragma unroll
    for (int m = 0; m < 4; ++m) acc[m] = (f32x4){0.f, 0.f, 0.f, 0.f};

    const int kq  = lane >> 4;
    const int r16 = lane & 15;

    auto compute = [&](int b) {
        #pragma unroll
        for (int s = 0; s < 2; ++s) {
            const int kb = (s << 2) + kq;
            const bf16x8 bf = *(const bf16x8*)&Bs[b][((kb << 6) + (wv << 4) + r16) << 3];
            #pragma unroll
            for (int m = 0; m < 4; ++m) {
                const bf16x8 af = *(const bf16x8*)&As[b][((kb << 6) + (m << 4) + r16) << 3];
                acc[m] = __builtin_amdgcn_mfma_f32_16x16x32_bf16(af, bf, acc[m], 0, 0, 0);
            }
        }
    };

    stage(0, 0);
    __syncthreads();
    int buf = 0;
    for (int t = 0; t < KC; ++t) {
        if (t + 1 < KC) stage(buf ^ 1, t + 1);
        compute(buf);
        __syncthreads();
        buf ^= 1;
    }

    const int col  = (bn << 6) + (wv << 4) + r16;
    const float bv = bias[col];
    #pragma unroll
    for (int m = 0; m < 4; ++m)
        #pragma unroll
        for (int j = 0; j < 4; ++j) {
            const float v = acc[m][j] + bv;
            const int row = (bp << 6) + (kq << 2) + (m << 4) + j;
            Cout[(size_t)row * Nout + col] = f2bf(v);
        }
}

// ---------------------------------------------------------------------------
// Edge MLP + fused zero-fill of the 67MB output.
// HALF-WAVE (32 lanes) per edge, 8 channels/lane via one uint4 load.
// grid 2048 x 256 = 8192 waves -> 16384 edges/sweep, 8 sweeps = 131072.
// Zero-stores issued first (write pipe), gathers overlap (L2/latency pipe).
// ---------------------------------------------------------------------------
__global__ __launch_bounds__(256)
void edge_mlp_fill(const u16* __restrict__ AB, const int* __restrict__ idx,
                   const float* __restrict__ We2, const float* __restrict__ be2p,
                   float* __restrict__ s, float* __restrict__ part,
                   float4* __restrict__ out4)
{
    __shared__ float sm[256];
    const int tid  = threadIdx.x;
    const int lane = tid & 63;
    const int sub  = lane >> 5;
    const int l5   = lane & 31;
    const int wid  = (blockIdx.x * 256 + tid) >> 6;     // 0..8191
    const float be2 = be2p[0];

    // zero-fill: 2048 blk * 256 thr * 8 float4 = 16.7M floats
    {
        float4* op = out4 + (size_t)blockIdx.x * 256 + tid;
        const float4 z = {0.f, 0.f, 0.f, 0.f};
        #pragma unroll
        for (int q = 0; q < 8; ++q)
            op[(size_t)q * 524288] = z;
    }

    float w2v[8];
    #pragma unroll
    for (int q = 0; q < 2; ++q) {
        const float4 w = ((const float4*)We2)[l5 * 2 + q];
        w2v[q * 4 + 0] = w.x; w2v[q * 4 + 1] = w.y;
        w2v[q * 4 + 2] = w.z; w2v[q * 4 + 3] = w.w;
    }

    float mloc = -3.0e38f;
    #pragma unroll
    for (int it = 0; it < 8; ++it) {
        const int e = (wid << 1) + sub + (it << 14);    // covers [0, 131072)
        const int src = idx[2 * e];
        const int dst = idx[2 * e + 1];
        const uint4 av = *(const uint4*)(AB + ((size_t)src << 9) + (l5 << 3));
        const uint4 bv = *(const uint4*)(AB + ((size_t)dst << 9) + 256 + (l5 << 3));
        const u32 aw[4] = {av.x, av.y, av.z, av.w};
        const u32 bw[4] = {bv.x, bv.y, bv.z, bv.w};
        float p = 0.0f;
        #pragma unroll
        for (int q = 0; q < 4; ++q) {
            p += fmaxf(bflo(aw[q]) + bflo(bw[q]), 0.0f) * w2v[2 * q];
            p += fmaxf(bfhi(aw[q]) + bfhi(bw[q]), 0.0f) * w2v[2 * q + 1];
        }
        #pragma unroll
        for (int m = 16; m > 0; m >>= 1)
            p += __shfl_xor(p, m, 64);   // xor<32: stays within the half-wave
        p += be2;
        if (l5 == 0) s[e] = p;
        mloc = fmaxf(mloc, p);
    }
    sm[tid] = mloc;
    __syncthreads();
    for (int st = 128; st > 0; st >>= 1) {
        if (tid < st) sm[tid] = fmaxf(sm[tid], sm[tid + st]);
        __syncthreads();
    }
    if (tid == 0) part[blockIdx.x] = sm[0];
}

// fused: finalize max over part[2048] (redundant per block) + partial sumexp
__global__ __launch_bounds__(256)
void sumexp_part(const float* __restrict__ s, const float* __restrict__ part,
                 int n, float* __restrict__ part2, float* __restrict__ g)
{
    __shared__ float sm[256];
    float m = part[threadIdx.x];
    #pragma unroll
    for (int k = 1; k < 8; ++k)
        m = fmaxf(m, part[threadIdx.x + k * 256]);
    sm[threadIdx.x] = m;
    __syncthreads();
    for (int st = 128; st > 0; st >>= 1) {
        if (threadIdx.x < st) sm[threadIdx.x] = fmaxf(sm[threadIdx.x], sm[threadIdx.x + st]);
        __syncthreads();
    }
    const float gm = sm[0];
    __syncthreads();
    float a = 0.0f;
    for (int i = blockIdx.x * 256 + threadIdx.x; i < n; i += 256 * gridDim.x)
        a += expf(s[i] - gm);
    sm[threadIdx.x] = a;
    __syncthreads();
    for (int st = 128; st > 0; st >>= 1) {
        if (threadIdx.x < st) sm[threadIdx.x] += sm[threadIdx.x + st];
        __syncthreads();
    }
    if (threadIdx.x == 0) {
        part2[blockIdx.x] = sm[0];
        if (blockIdx.x == 0) g[0] = gm;
    }
}

// fused: finalize sum (redundant per block) + scatter probs
__global__ __launch_bounds__(256)
void scatter_probs(const float* __restrict__ s, const int* __restrict__ idx,
                   const float* __restrict__ part2, const float* __restrict__ g,
                   float* __restrict__ out, int n)
{
    __shared__ float sm[256];
    sm[threadIdx.x] = part2[threadIdx.x];
    __syncthreads();
    for (int st = 128; st > 0; st >>= 1) {
        if (threadIdx.x < st) sm[threadIdx.x] += sm[threadIdx.x + st];
        __syncthreads();
    }
    const float Z = sm[0];
    const float gm = g[0];
    const int e = blockIdx.x * 256 + threadIdx.x;
    if (e < n)
        out[(size_t)idx[2 * e] * N_NODES + idx[2 * e + 1]] = expf(s[e] - gm) / Z;
}

// ---------------------------------------------------------------------------
extern "C" void kernel_launch(void* const* d_in, const int* in_sizes, int n_in,
                              void* d_out, int out_size, void* d_ws, size_t ws_size,
                              hipStream_t stream)
{
    const float* ideal = (const float*)d_in[0];   // 4096 x 1024
    const int*   idx   = (const int*)d_in[1];     // E x 2
    const float* W1    = (const float*)d_in[2];   // 256 x 1024
    const float* b1    = (const float*)d_in[3];   // 256
    const float* W2    = (const float*)d_in[4];   // 256 x 256
    const float* b2    = (const float*)d_in[5];   // 256
    const float* We1   = (const float*)d_in[6];   // 256 x 512
    const float* be1   = (const float*)d_in[7];   // 256
    const float* We2   = (const float*)d_in[8];   // 256
    const float* be2   = (const float*)d_in[9];   // 1
    float* out = (float*)d_out;

    char* Wb = (char*)d_ws;
    u16*   xh   = (u16*)(Wb);                          // 8 MB packed x
    u16*   w1h  = (u16*)(Wb + (8u << 20));             // 512 KB packed W1
    u16*   wabh = (u16*)(Wb + (8u << 20) + (512u << 10)); // 256 KB packed Wab
    u16*   h1h  = (u16*)(Wb + (9u << 20));             // 2 MB packed h1
    float* bab  = (float*)(Wb + (11u << 20));          // 2 KB
    u16*   ABbf = (u16*)(Wb + (12u << 20));            // 4 MB bf16 AB row-major
    float* sbuf = (float*)(Wb + (16u << 20));          // 512 KB scores
    float* part = sbuf + E_EDGES;                      // 2048
    float* part2 = part + 2048;                        // 256
    float* g    = part2 + 256;                         // 1

    prep_all<<<2242, 256, 0, stream>>>(ideal, W1, We1, W2, b2, be1, xh, w1h, wabh, bab);

    // h1 packed = relu(x @ W1.T + b1)   (512 blocks, 2/CU)
    mfma_gemm1<<<dim3(128, 4), 256, 0, stream>>>(xh, w1h, b1, h1h);
    // AB bf16 = h1 @ Wab.T + bab        (N = 512: [A | B])
    mfma_gemm2<<<dim3(64, 8), 256, 0, stream>>>(h1h, wabh, bab, ABbf);

    edge_mlp_fill<<<2048, 256, 0, stream>>>(ABbf, idx, We2, be2, sbuf, part, (float4*)out);
    sumexp_part<<<256, 256, 0, stream>>>(sbuf, part, E_EDGES, part2, g);
    scatter_probs<<<512, 256, 0, stream>>>(sbuf, idx, part2, g, out, E_EDGES);
}